// Round 1
// baseline (181.502 us; speedup 1.0000x reference)
//
#include <hip/hip_runtime.h>

// Involution fused kernels for MI355X (gfx950), fp32.
// x: (4,256,56,56), w1: (64,256), bn params (64), w2: (784,64), b2: (784)
// out: (4,256,56,56)

#define HW    3136
#define WIDE  56
#define C_IN  256
#define CR    64
#define NG    16
#define GC    16
#define KK    49
#define BN_EPS 1e-5f

// Kernel 1: y = relu(bn(w1 @ x)), y -> workspace, layout (b, 64, 3136)
// Block: 256 threads = 64 pixels x 4 output-quarters (16 outputs each).
// w1 reads are wave-uniform (oq readfirstlane'd) -> scalar loads, no LDS.
__global__ __launch_bounds__(256) void conv1_bn_relu(
    const float* __restrict__ x, const float* __restrict__ w1,
    const float* __restrict__ gamma, const float* __restrict__ beta,
    const float* __restrict__ mean, const float* __restrict__ var,
    float* __restrict__ y)
{
    const int tid  = threadIdx.x;
    const int lane = tid & 63;
    const int oq   = __builtin_amdgcn_readfirstlane(tid >> 6); // wave-uniform
    const int P    = blockIdx.x * 64 + lane;   // global pixel id over (b,hw)
    const int b    = P / HW;
    const int hw   = P - b * HW;

    const float* __restrict__ xb  = x + (size_t)b * C_IN * HW + hw;
    const float* __restrict__ w1u = w1 + (size_t)(oq * 16) * C_IN;

    float acc[16];
#pragma unroll
    for (int u = 0; u < 16; ++u) acc[u] = 0.f;

#pragma unroll 4
    for (int c = 0; c < C_IN; ++c) {
        const float xv = xb[(size_t)c * HW];
#pragma unroll
        for (int u = 0; u < 16; ++u)
            acc[u] += w1u[u * C_IN + c] * xv;   // uniform addr -> s_load
    }

    const int obase = oq * 16;
#pragma unroll
    for (int u = 0; u < 16; ++u) {
        const int o = obase + u;
        const float s  = gamma[o] * rsqrtf(var[o] + BN_EPS);
        const float sh = beta[o] - mean[o] * s;
        const float v  = fmaxf(acc[u] * s + sh, 0.f);
        y[((size_t)b * CR + o) * HW + hw] = v;
    }
}

// Kernel 2: fused conv2 (-> per-pixel 49-tap kernels, kept in VGPRs) +
// involution multiply-reduce. One thread per (b, g, pixel).
// w2/b2 reads are block-uniform (g from blockIdx) -> scalar loads.
__global__ __launch_bounds__(256) void conv2_involution(
    const float* __restrict__ x, const float* __restrict__ y,
    const float* __restrict__ w2, const float* __restrict__ b2,
    float* __restrict__ out)
{
    const int hw = blockIdx.x * 256 + threadIdx.x;
    if (hw >= HW) return;
    const int g = blockIdx.y & 15;
    const int b = blockIdx.y >> 4;
    const int h = hw / WIDE;
    const int w = hw - h * WIDE;

    const float* __restrict__ w2g = w2 + (size_t)g * KK * CR;
    const float* __restrict__ b2g = b2 + g * KK;

    float kw[KK];
#pragma unroll
    for (int k = 0; k < KK; ++k) kw[k] = b2g[k];   // uniform -> s_load

    // conv2: kw[k] += sum_c w2[g*49+k][c] * y[b][c][hw]
    const float* __restrict__ yb = y + (size_t)b * CR * HW + hw;
#pragma unroll 2
    for (int c = 0; c < CR; ++c) {
        const float yv = yb[(size_t)c * HW];
#pragma unroll
        for (int k = 0; k < KK; ++k)
            kw[k] += w2g[k * CR + c] * yv;          // uniform -> s_load
    }

    // involution: out[b][g*16+cg][hw] = sum_{i,j} kw[i*7+j] * xpad[...]
    const float* __restrict__ xb = x + ((size_t)b * C_IN + g * GC) * HW;
    float* __restrict__ ob = out + ((size_t)b * C_IN + g * GC) * HW + hw;

#pragma unroll 1
    for (int cg = 0; cg < GC; ++cg) {
        const float* __restrict__ xc = xb + (size_t)cg * HW;
        float s = 0.f;
#pragma unroll
        for (int i = 0; i < 7; ++i) {
            const int hh = h + i - 3;
            const bool rv = (hh >= 0) & (hh < WIDE);
            const int hhc = min(max(hh, 0), WIDE - 1);
            const float* __restrict__ xrow = xc + hhc * WIDE;
#pragma unroll
            for (int j = 0; j < 7; ++j) {
                const int ww = w + j - 3;
                const bool cv = rv & ((ww >= 0) & (ww < WIDE));
                const int wwc = min(max(ww, 0), WIDE - 1);
                const float xv = xrow[wwc];
                s += kw[i * 7 + j] * (cv ? xv : 0.f);
            }
        }
        ob[(size_t)cg * HW] = s;
    }
}

extern "C" void kernel_launch(void* const* d_in, const int* in_sizes, int n_in,
                              void* d_out, int out_size, void* d_ws, size_t ws_size,
                              hipStream_t stream) {
    const float* x     = (const float*)d_in[0];
    const float* w1    = (const float*)d_in[1];
    const float* gamma = (const float*)d_in[2];
    const float* beta  = (const float*)d_in[3];
    const float* mean  = (const float*)d_in[4];
    const float* var   = (const float*)d_in[5];
    const float* w2    = (const float*)d_in[6];
    const float* b2    = (const float*)d_in[7];
    float* out = (float*)d_out;
    float* y   = (float*)d_ws;   // 4*64*3136 floats = 3.2 MB

    // Kernel 1: 4*3136 pixels / 64 per block = 196 blocks
    conv1_bn_relu<<<dim3(196), dim3(256), 0, stream>>>(x, w1, gamma, beta, mean, var, y);

    // Kernel 2: grid (13 pixel-tiles of 256, 64 = b*g), 256 threads
    conv2_involution<<<dim3(13, 64), dim3(256), 0, stream>>>(x, y, w2, b2, out);
}

// Round 2
// 84.333 us; speedup vs baseline: 2.1522x; 2.1522x over previous
//
#include <hip/hip_runtime.h>

// Involution fused kernels for MI355X (gfx950), fp32.
// x: (4,256,56,56), w1: (64,256), bn params (64), w2: (784,64), b2: (784)
// out: (4,256,56,56)

#define HW    3136
#define WIDE  56
#define C_IN  256
#define CR    64
#define NG    16
#define GC    16
#define KK    49
#define BN_EPS 1e-5f

// Kernel 1: y = relu(bn(w1 @ x)), y -> workspace, layout (b, 64, 3136)
// Block: 256 threads = 64 pixels x 4 output-octs (8 outputs each);
// blockIdx.y supplies the other oct bit -> 392 blocks, 1568 waves.
// w1 reads are wave-uniform (oct readfirstlane'd) -> scalar loads.
__global__ __launch_bounds__(256) void conv1_bn_relu(
    const float* __restrict__ x, const float* __restrict__ w1,
    const float* __restrict__ gamma, const float* __restrict__ beta,
    const float* __restrict__ mean, const float* __restrict__ var,
    float* __restrict__ y)
{
    const int tid  = threadIdx.x;
    const int lane = tid & 63;
    const int oct  = __builtin_amdgcn_readfirstlane((blockIdx.y << 2) | (tid >> 6)); // 0..7
    const int P    = blockIdx.x * 64 + lane;   // global pixel id over (b,hw)
    const int b    = P / HW;
    const int hw   = P - b * HW;

    const float* __restrict__ xb  = x + (size_t)b * C_IN * HW + hw;
    const float* __restrict__ w1u = w1 + (size_t)(oct * 8) * C_IN;

    float acc[8];
#pragma unroll
    for (int u = 0; u < 8; ++u) acc[u] = 0.f;

#pragma unroll 8
    for (int c = 0; c < C_IN; ++c) {
        const float xv = xb[(size_t)c * HW];
#pragma unroll
        for (int u = 0; u < 8; ++u)
            acc[u] += w1u[u * C_IN + c] * xv;   // uniform addr -> s_load
    }

    const int obase = oct * 8;
#pragma unroll
    for (int u = 0; u < 8; ++u) {
        const int o = obase + u;
        const float s  = gamma[o] * rsqrtf(var[o] + BN_EPS);
        const float sh = beta[o] - mean[o] * s;
        const float v  = fmaxf(acc[u] * s + sh, 0.f);
        y[((size_t)b * CR + o) * HW + hw] = v;
    }
}

// Kernel 2: fused conv2 + involution, one block per (b, g, 64-pixel tile).
// Phase 1: 256 threads compute the 64-pixel x 49-tap kernel field into LDS.
//          thread = (pixel p = tid&63, wave q = tid>>6); k = q + 4*m so the
//          w2/b2 addresses are wave-uniform -> s_loads.
// Phase 2: wave q handles channels [q*4, q*4+4) for all 64 pixels.
// LDS kw[64][49]: lane stride 49 floats -> only 2-way bank aliasing (free).
__global__ __launch_bounds__(256) void conv2_involution(
    const float* __restrict__ x, const float* __restrict__ y,
    const float* __restrict__ w2, const float* __restrict__ b2,
    float* __restrict__ out)
{
    __shared__ float kw_lds[64][KK];

    const int tid = threadIdx.x;
    const int p   = tid & 63;                                   // pixel in tile
    const int q   = __builtin_amdgcn_readfirstlane(tid >> 6);   // wave id 0..3
    const int hw  = blockIdx.x * 64 + p;                        // 49*64 = 3136 exact
    const int g   = blockIdx.y & 15;
    const int b   = blockIdx.y >> 4;

    // ---- Phase 1: kw[p][k] = b2[g*49+k] + sum_c w2[g*49+k][c] * y[b][c][hw]
    {
        const float* __restrict__ w2g = w2 + (size_t)g * KK * CR;
        const float* __restrict__ b2g = b2 + g * KK;
        const float* __restrict__ yb  = y + (size_t)b * CR * HW + hw;

        float acc[13];
#pragma unroll
        for (int m = 0; m < 13; ++m) {
            const int k = min(q + 4 * m, KK - 1);
            acc[m] = b2g[k];                      // uniform -> s_load
        }
#pragma unroll 4
        for (int c = 0; c < CR; ++c) {
            const float yv = yb[(size_t)c * HW];
#pragma unroll
            for (int m = 0; m < 13; ++m) {
                const int k = min(q + 4 * m, KK - 1);
                acc[m] += w2g[k * CR + c] * yv;   // uniform -> s_load
            }
        }
#pragma unroll
        for (int m = 0; m < 13; ++m) {
            const int k = q + 4 * m;
            if (k < KK) kw_lds[p][k] = acc[m];
        }
    }
    __syncthreads();

    // ---- Phase 2: involution. Thread: pixel p, channels q*4 .. q*4+3.
    const int h = hw / WIDE;
    const int w = hw - h * WIDE;
    const float* __restrict__ xc =
        x + ((size_t)b * C_IN + g * GC + q * 4) * HW;

    float s0 = 0.f, s1 = 0.f, s2 = 0.f, s3 = 0.f;
#pragma unroll
    for (int i = 0; i < 7; ++i) {
        const int hh = h + i - 3;
        const bool rv = (hh >= 0) & (hh < WIDE);
        const int hhc = min(max(hh, 0), WIDE - 1);
        const int rowoff = hhc * WIDE;
#pragma unroll
        for (int j = 0; j < 7; ++j) {
            const int ww = w + j - 3;
            const bool cv = rv & ((ww >= 0) & (ww < WIDE));
            const int wwc = min(max(ww, 0), WIDE - 1);
            const int off = rowoff + wwc;
            const float kwv = kw_lds[p][i * 7 + j];
            const float x0 = xc[off];
            const float x1 = xc[HW + off];
            const float x2 = xc[2 * HW + off];
            const float x3 = xc[3 * HW + off];
            s0 += kwv * (cv ? x0 : 0.f);
            s1 += kwv * (cv ? x1 : 0.f);
            s2 += kwv * (cv ? x2 : 0.f);
            s3 += kwv * (cv ? x3 : 0.f);
        }
    }

    float* __restrict__ ob = out + ((size_t)b * C_IN + g * GC + q * 4) * HW + hw;
    ob[0]          = s0;
    ob[(size_t)HW]     = s1;
    ob[(size_t)2 * HW] = s2;
    ob[(size_t)3 * HW] = s3;
}

extern "C" void kernel_launch(void* const* d_in, const int* in_sizes, int n_in,
                              void* d_out, int out_size, void* d_ws, size_t ws_size,
                              hipStream_t stream) {
    const float* x     = (const float*)d_in[0];
    const float* w1    = (const float*)d_in[1];
    const float* gamma = (const float*)d_in[2];
    const float* beta  = (const float*)d_in[3];
    const float* mean  = (const float*)d_in[4];
    const float* var   = (const float*)d_in[5];
    const float* w2    = (const float*)d_in[6];
    const float* b2    = (const float*)d_in[7];
    float* out = (float*)d_out;
    float* y   = (float*)d_ws;   // 4*64*3136 floats = 3.2 MB

    // Kernel 1: (12544 px / 64) x 2 oct-halves = 392 blocks
    conv1_bn_relu<<<dim3(196, 2), dim3(256), 0, stream>>>(x, w1, gamma, beta, mean, var, y);

    // Kernel 2: grid (49 pixel-tiles of 64, 64 = b*g), 256 threads
    conv2_involution<<<dim3(49, 64), dim3(256), 0, stream>>>(x, y, w2, b2, out);
}

// Round 3
// 77.929 us; speedup vs baseline: 2.3291x; 1.0822x over previous
//
#include <hip/hip_runtime.h>

// Involution fused kernels for MI355X (gfx950), fp32.
// x: (4,256,56,56), w1: (64,256), bn params (64), w2: (784,64), b2: (784)
// out: (4,256,56,56)

#define HW    3136
#define WIDE  56
#define C_IN  256
#define CR    64
#define NG    16
#define GC    16
#define KK    49
#define BN_EPS 1e-5f

// Kernel 1: y = relu(bn(w1 @ x)), y -> workspace, layout (b, 64, 3136)
// 512 threads = 8 waves; block stages x[256c][64px] tile into 64KB LDS
// (2 blocks/CU -> 16 waves/CU), wave q computes outputs q*8..q*8+7.
// xs[c][lane]: 2-way bank alias only (free). w1 via scalar loads.
__global__ __launch_bounds__(512) void conv1_bn_relu(
    const float* __restrict__ x, const float* __restrict__ w1,
    const float* __restrict__ gamma, const float* __restrict__ beta,
    const float* __restrict__ mean, const float* __restrict__ var,
    float* __restrict__ y)
{
    __shared__ float xs[C_IN * 64];   // 64 KB

    const int t    = threadIdx.x;
    const int lane = t & 63;
    const int wq   = __builtin_amdgcn_readfirstlane(t >> 6);  // 0..7
    const int tile = blockIdx.x;          // 0..195
    const int b    = tile / 49;
    const int hw   = (tile - b * 49) * 64 + lane;

    const float* __restrict__ xb = x + (size_t)b * C_IN * HW + hw;

    // stage: wave q loads channels [wq*32, wq*32+32)
#pragma unroll
    for (int it = 0; it < 32; ++it) {
        const int c = wq * 32 + it;
        xs[c * 64 + lane] = xb[(size_t)c * HW];
    }
    __syncthreads();

    const float* __restrict__ w1u = w1 + (size_t)(wq * 8) * C_IN;
    float acc[8];
#pragma unroll
    for (int u = 0; u < 8; ++u) acc[u] = 0.f;

#pragma unroll 4
    for (int c = 0; c < C_IN; ++c) {
        const float xv = xs[c * 64 + lane];
#pragma unroll
        for (int u = 0; u < 8; ++u)
            acc[u] += w1u[u * C_IN + c] * xv;   // uniform addr -> s_load
    }

    const int obase = wq * 8;
#pragma unroll
    for (int u = 0; u < 8; ++u) {
        const int o = obase + u;
        const float s  = gamma[o] * rsqrtf(var[o] + BN_EPS);
        const float sh = beta[o] - mean[o] * s;
        const float v  = fmaxf(acc[u] * s + sh, 0.f);
        y[((size_t)b * CR + o) * HW + hw] = v;
    }
}

// Kernel 2: fused conv2 + involution, one block per (b, g, 64-pixel tile).
// Phase 1: 256 threads compute 64px x 49-tap kernel field; out-of-bounds
//          taps are ZEROED AT WRITE time (same pixel p as the reader), so
//          phase 2 needs no validity logic at all.
// Phase 2: wave q handles channels [q*4, q*4+4). Per tap: idx clamped into
//          the channel plane (v_med3) -> 4 loads off wave-uniform SGPR
//          bases + 4 FMA + 1 ds_read. Garbage loads are multiplied by 0.
__global__ __launch_bounds__(256) void conv2_involution(
    const float* __restrict__ x, const float* __restrict__ y,
    const float* __restrict__ w2, const float* __restrict__ b2,
    float* __restrict__ out)
{
    __shared__ float kw_lds[64 * KK];

    const int tid = threadIdx.x;
    const int p   = tid & 63;                                   // pixel in tile
    const int q   = __builtin_amdgcn_readfirstlane(tid >> 6);   // wave id 0..3
    const int hw  = blockIdx.x * 64 + p;                        // 49*64 = 3136
    const int g   = blockIdx.y & 15;
    const int b   = blockIdx.y >> 4;
    const int h   = hw / WIDE;
    const int w   = hw - h * WIDE;

    // ---- Phase 1: kw[p][k] = mask * (b2[g*49+k] + sum_c w2[g*49+k][c]*y[b][c][hw])
    {
        const float* __restrict__ w2g = w2 + (size_t)g * KK * CR;
        const float* __restrict__ b2g = b2 + g * KK;
        const float* __restrict__ yb  = y + (size_t)b * CR * HW + hw;

        float acc[13];
#pragma unroll
        for (int m = 0; m < 13; ++m) {
            const int k = min(q + 4 * m, KK - 1);
            acc[m] = b2g[k];                      // uniform -> s_load
        }
#pragma unroll 4
        for (int c = 0; c < CR; ++c) {
            const float yv = yb[(size_t)c * HW];
#pragma unroll
            for (int m = 0; m < 13; ++m) {
                const int k = min(q + 4 * m, KK - 1);
                acc[m] += w2g[k * CR + c] * yv;   // uniform -> s_load
            }
        }
#pragma unroll
        for (int m = 0; m < 13; ++m) {
            const int k = q + 4 * m;
            if (k < KK) {
                const int i  = k / 7;
                const int j  = k - i * 7;
                const int rr = h + i - 3;
                const int cc = w + j - 3;
                const bool v = (rr >= 0) & (rr < WIDE) & (cc >= 0) & (cc < WIDE);
                kw_lds[p * KK + k] = v ? acc[m] : 0.f;
            }
        }
    }
    __syncthreads();

    // ---- Phase 2: involution. Thread: pixel p, channels q*4 .. q*4+3.
    const float* __restrict__ xq0 = x + ((size_t)b * C_IN + g * GC + q * 4) * HW;
    const float* __restrict__ xq1 = xq0 + HW;
    const float* __restrict__ xq2 = xq0 + 2 * HW;
    const float* __restrict__ xq3 = xq0 + 3 * HW;

    float s0 = 0.f, s1 = 0.f, s2 = 0.f, s3 = 0.f;
    const int lbase = p * KK;

#pragma unroll
    for (int i = 0; i < 7; ++i) {
        const int idx0 = hw + (i - 3) * WIDE - 3;
#pragma unroll
        for (int j = 0; j < 7; ++j) {
            const int idxc = min(max(idx0 + j, 0), HW - 1);   // v_med3_i32
            const float kwv = kw_lds[lbase + i * 7 + j];      // 0 if OOB tap
            s0 += kwv * xq0[idxc];
            s1 += kwv * xq1[idxc];
            s2 += kwv * xq2[idxc];
            s3 += kwv * xq3[idxc];
        }
    }

    float* __restrict__ ob = out + ((size_t)b * C_IN + g * GC + q * 4) * HW + hw;
    ob[0]              = s0;
    ob[(size_t)HW]     = s1;
    ob[(size_t)2 * HW] = s2;
    ob[(size_t)3 * HW] = s3;
}

extern "C" void kernel_launch(void* const* d_in, const int* in_sizes, int n_in,
                              void* d_out, int out_size, void* d_ws, size_t ws_size,
                              hipStream_t stream) {
    const float* x     = (const float*)d_in[0];
    const float* w1    = (const float*)d_in[1];
    const float* gamma = (const float*)d_in[2];
    const float* beta  = (const float*)d_in[3];
    const float* mean  = (const float*)d_in[4];
    const float* var   = (const float*)d_in[5];
    const float* w2    = (const float*)d_in[6];
    const float* b2    = (const float*)d_in[7];
    float* out = (float*)d_out;
    float* y   = (float*)d_ws;   // 4*64*3136 floats = 3.2 MB

    // Kernel 1: 196 blocks x 512 threads, 64KB LDS each
    conv1_bn_relu<<<dim3(196), dim3(512), 0, stream>>>(x, w1, gamma, beta, mean, var, y);

    // Kernel 2: grid (49 pixel-tiles of 64, 64 = b*g), 256 threads
    conv2_involution<<<dim3(49, 64), dim3(256), 0, stream>>>(x, y, w2, b2, out);
}

// Round 4
// 67.353 us; speedup vs baseline: 2.6948x; 1.1570x over previous
//
#include <hip/hip_runtime.h>

// Involution fused kernels for MI355X (gfx950).
// x: (4,256,56,56) f32, w1: (64,256), bn(64), w2: (784,64), b2: (784)
// out: (4,256,56,56) f32
// ws layout: ybf16 [4][3136][64] | wprep bf16 [16][64][64] | b2pad f32 [16][64] | w1T f32 [256][64]

#define HW    3136
#define WIDE  56
#define C_IN  256
#define CR    64
#define GC    16
#define KK    49
#define BN_EPS 1e-5f

typedef __attribute__((ext_vector_type(8))) short short8;
typedef __attribute__((ext_vector_type(4))) float f32x4;
typedef __attribute__((ext_vector_type(4))) unsigned int u32x4;

__device__ __forceinline__ unsigned short f2bf(float f) {
    unsigned u = __float_as_uint(f);
    unsigned r = (u + 0x7FFFu + ((u >> 16) & 1u)) >> 16;   // RNE
    return (unsigned short)r;
}

// ---- Prep: w1T[c][o] f32; wprep[g][k][c] bf16 (k>=49 zero); b2pad[g][k] f32 ----
__global__ __launch_bounds__(256) void prep_kernel(
    const float* __restrict__ w1, const float* __restrict__ w2,
    const float* __restrict__ b2,
    float* __restrict__ w1T, unsigned short* __restrict__ wprep,
    float* __restrict__ b2pad)
{
    const int t = blockIdx.x * 256 + threadIdx.x;   // 0..65535
    if (t < 16384) {                                // w1T: c=t>>6, o=t&63
        const int c = t >> 6, o = t & 63;
        w1T[c * 64 + o] = w1[o * C_IN + c];
    }
    {                                               // wprep: g=t>>12, k=(t>>6)&63, c=t&63
        const int g = t >> 12, k = (t >> 6) & 63, c = t & 63;
        wprep[t] = (k < KK) ? f2bf(w2[(size_t)(g * KK + k) * CR + c]) : (unsigned short)0;
    }
    if (t < 1024) {                                 // b2pad
        const int g = t >> 6, k = t & 63;
        b2pad[t] = (k < KK) ? b2[g * KK + k] : 0.f;
    }
}

// ---- Kernel 1: y = relu(bn(w1 @ x)) -> bf16, layout [b][px][c] ----
// 512 thr: wave q computes outputs q*8..q*8+7 for 64 px. x staged in LDS.
// w1T row slice is ONE contiguous 32B wave-uniform scalar load per K-iter.
__global__ __launch_bounds__(512) void conv1_bn_relu(
    const float* __restrict__ x, const float* __restrict__ w1T,
    const float* __restrict__ gamma, const float* __restrict__ beta,
    const float* __restrict__ mean, const float* __restrict__ var,
    unsigned short* __restrict__ ybf)
{
    __shared__ float xs[C_IN * 64];   // 64 KB

    const int t    = threadIdx.x;
    const int lane = t & 63;
    const int wq   = __builtin_amdgcn_readfirstlane(t >> 6);  // 0..7
    const int tile = blockIdx.x;          // 0..195
    const int b    = tile / 49;
    const int hw   = (tile - b * 49) * 64 + lane;

    const float* __restrict__ xb = x + (size_t)b * C_IN * HW + hw;
#pragma unroll
    for (int it = 0; it < 32; ++it) {
        const int c = wq * 32 + it;
        xs[c * 64 + lane] = xb[(size_t)c * HW];
    }
    __syncthreads();

    float acc[8];
#pragma unroll
    for (int u = 0; u < 8; ++u) acc[u] = 0.f;

#pragma unroll 4
    for (int c = 0; c < C_IN; ++c) {
        const float xv = xs[c * 64 + lane];
        const float* __restrict__ wr = w1T + c * 64 + wq * 8;  // uniform, 32B contiguous
#pragma unroll
        for (int u = 0; u < 8; ++u)
            acc[u] += wr[u] * xv;
    }

    unsigned short o8[8];
#pragma unroll
    for (int u = 0; u < 8; ++u) {
        const int o = wq * 8 + u;
        const float s  = gamma[o] * rsqrtf(var[o] + BN_EPS);
        const float sh = beta[o] - mean[o] * s;
        o8[u] = f2bf(fmaxf(acc[u] * s + sh, 0.f));
    }
    u32x4 pack;
    pack.x = (unsigned)o8[0] | ((unsigned)o8[1] << 16);
    pack.y = (unsigned)o8[2] | ((unsigned)o8[3] << 16);
    pack.z = (unsigned)o8[4] | ((unsigned)o8[5] << 16);
    pack.w = (unsigned)o8[6] | ((unsigned)o8[7] << 16);
    *(u32x4*)(ybf + ((size_t)(b * HW + hw)) * 64 + wq * 8) = pack;
}

// ---- Kernel 2: MFMA conv2 (phase 1) + involution (phase 2) ----
// Block = (b, g, 64-px tile). Phase 1: wave q computes kw[64k][16px] via
// 8x mfma_f32_16x16x32_bf16 (A = wprep[g] 64x64, B = y tile 64x16),
// adds bias, zeroes OOB taps, stores kw_lds[k][px]. Phase 2: wave q does
// channels q*4..q*4+3 for pixel p=lane; per tap: med3-clamped idx, 4 loads
// off wave-uniform bases, 4 FMA, 1 conflict-free ds_read.
__global__ __launch_bounds__(256) void conv2_involution(
    const float* __restrict__ x, const unsigned short* __restrict__ ybf,
    const unsigned short* __restrict__ wprep, const float* __restrict__ b2pad,
    float* __restrict__ out)
{
    __shared__ float kw_lds[64 * 64];   // [k][px], 16 KB

    const int tid  = threadIdx.x;
    const int lane = tid & 63;
    const int q    = __builtin_amdgcn_readfirstlane(tid >> 6);  // wave 0..3
    const int tile = blockIdx.x;                                // 0..48
    const int g    = blockIdx.y & 15;
    const int b    = blockIdx.y >> 4;
    const int l15  = lane & 15;
    const int lg   = lane >> 4;

    // ---- Phase 1: MFMA ----
    {
        const int px  = q * 16 + l15;           // pixel col this lane owns
        const int hwp = tile * 64 + px;
        // B fragments: y[b][hwp][c], c = lg*8+e (+32 for kstep 1)
        const unsigned short* ybase = ybf + ((size_t)(b * HW + hwp)) * 64 + lg * 8;
        const short8 B0 = *(const short8*)(ybase);
        const short8 B1 = *(const short8*)(ybase + 32);

        const unsigned short* wg = wprep + g * 4096;
        f32x4 acc[4];
#pragma unroll
        for (int rt = 0; rt < 4; ++rt) acc[rt] = (f32x4){0.f, 0.f, 0.f, 0.f};

#pragma unroll
        for (int rt = 0; rt < 4; ++rt) {
            const unsigned short* arow = wg + (rt * 16 + l15) * 64 + lg * 8;
            const short8 A0 = *(const short8*)(arow);
            const short8 A1 = *(const short8*)(arow + 32);
            acc[rt] = __builtin_amdgcn_mfma_f32_16x16x32_bf16(A0, B0, acc[rt], 0, 0, 0);
            acc[rt] = __builtin_amdgcn_mfma_f32_16x16x32_bf16(A1, B1, acc[rt], 0, 0, 0);
        }

        const int hp = hwp / WIDE;
        const int wp = hwp - hp * WIDE;
#pragma unroll
        for (int rt = 0; rt < 4; ++rt) {
#pragma unroll
            for (int r = 0; r < 4; ++r) {
                const int k = rt * 16 + lg * 4 + r;   // tap row of C/D
                const float val = acc[rt][r] + b2pad[g * 64 + k];
                const int i7 = k / 7, j7 = k - i7 * 7;
                const int rr = hp + i7 - 3, cc = wp + j7 - 3;
                const bool valid = (k < KK) & (rr >= 0) & (rr < WIDE) &
                                   (cc >= 0) & (cc < WIDE);
                kw_lds[k * 64 + px] = valid ? val : 0.f;
            }
        }
    }
    __syncthreads();

    // ---- Phase 2: involution. p = lane, channels q*4..q*4+3 ----
    const int hw = tile * 64 + lane;
    const float* __restrict__ xq0 = x + ((size_t)b * C_IN + g * GC + q * 4) * HW;
    const float* __restrict__ xq1 = xq0 + HW;
    const float* __restrict__ xq2 = xq0 + 2 * HW;
    const float* __restrict__ xq3 = xq0 + 3 * HW;

    float s0 = 0.f, s1 = 0.f, s2 = 0.f, s3 = 0.f;
#pragma unroll
    for (int i = 0; i < 7; ++i) {
        const int idx0 = hw + (i - 3) * WIDE - 3;
#pragma unroll
        for (int j = 0; j < 7; ++j) {
            const int idxc = min(max(idx0 + j, 0), HW - 1);   // v_med3_i32
            const float kwv = kw_lds[(i * 7 + j) * 64 + lane];
            s0 += kwv * xq0[idxc];
            s1 += kwv * xq1[idxc];
            s2 += kwv * xq2[idxc];
            s3 += kwv * xq3[idxc];
        }
    }

    float* __restrict__ ob = out + ((size_t)b * C_IN + g * GC + q * 4) * HW + hw;
    ob[0]              = s0;
    ob[(size_t)HW]     = s1;
    ob[(size_t)2 * HW] = s2;
    ob[(size_t)3 * HW] = s3;
}

extern "C" void kernel_launch(void* const* d_in, const int* in_sizes, int n_in,
                              void* d_out, int out_size, void* d_ws, size_t ws_size,
                              hipStream_t stream) {
    const float* x     = (const float*)d_in[0];
    const float* w1    = (const float*)d_in[1];
    const float* gamma = (const float*)d_in[2];
    const float* beta  = (const float*)d_in[3];
    const float* mean  = (const float*)d_in[4];
    const float* var   = (const float*)d_in[5];
    const float* w2    = (const float*)d_in[6];
    const float* b2    = (const float*)d_in[7];
    float* out = (float*)d_out;

    char* ws = (char*)d_ws;
    unsigned short* ybf   = (unsigned short*)(ws);             // 1,605,632 B
    unsigned short* wprep = (unsigned short*)(ws + 1605632);   //   131,072 B
    float*          b2pad = (float*)(ws + 1736704);            //     4,096 B
    float*          w1T   = (float*)(ws + 1740800);            //    65,536 B

    prep_kernel<<<dim3(256), dim3(256), 0, stream>>>(w1, w2, b2, w1T, wprep, b2pad);
    conv1_bn_relu<<<dim3(196), dim3(512), 0, stream>>>(x, w1T, gamma, beta, mean, var, ybf);
    conv2_involution<<<dim3(49, 64), dim3(256), 0, stream>>>(x, ybf, wprep, b2pad, out);
}

// Round 5
// 53.762 us; speedup vs baseline: 3.3760x; 1.2528x over previous
//
#include <hip/hip_runtime.h>

// Involution fused kernels for MI355X (gfx950).
// x: (4,256,56,56) f32, w1: (64,256), bn(64), w2: (784,64), b2: (784)
// out: (4,256,56,56) f32
// ws: ybf16 [4][3136][64] | wprep bf16 [16][64][64] | b2pad f32 [16][64] | w1T f32 [256][64]

#define HW    3136
#define WIDE  56
#define C_IN  256
#define CR    64
#define GC    16
#define KK    49
#define BN_EPS 1e-5f

typedef __attribute__((ext_vector_type(8))) short short8;
typedef __attribute__((ext_vector_type(4))) float f32x4;
typedef __attribute__((ext_vector_type(2))) unsigned int u32x2;

__device__ __forceinline__ unsigned short f2bf(float f) {
    unsigned u = __float_as_uint(f);
    return (unsigned short)((u + 0x7FFFu + ((u >> 16) & 1u)) >> 16);   // RNE
}

// ---- Prep: w1T[c][o] f32; wprep[g][k][c] bf16 (k>=49 zero); b2pad[g][k] f32 ----
__global__ __launch_bounds__(256) void prep_kernel(
    const float* __restrict__ w1, const float* __restrict__ w2,
    const float* __restrict__ b2,
    float* __restrict__ w1T, unsigned short* __restrict__ wprep,
    float* __restrict__ b2pad)
{
    const int t = blockIdx.x * 256 + threadIdx.x;   // 0..65535
    if (t < 16384) {                                // w1T: c=t>>6, o=t&63
        const int c = t >> 6, o = t & 63;
        w1T[c * 64 + o] = w1[o * C_IN + c];
    }
    {                                               // wprep: g=t>>12, k=(t>>6)&63, c=t&63
        const int g = t >> 12, k = (t >> 6) & 63, c = t & 63;
        wprep[t] = (k < KK) ? f2bf(w2[(size_t)(g * KK + k) * CR + c]) : (unsigned short)0;
    }
    if (t < 1024) {                                 // b2pad
        const int g = t >> 6, k = t & 63;
        b2pad[t] = (k < KK) ? b2[g * KK + k] : 0.f;
    }
}

// ---- Kernel 1: y = relu(bn(w1 @ x)) -> bf16, layout [b][px][c] ----
// grid (196 px-tiles, 4 og-quads) x 256 thr. Wave w computes outs
// (blockIdx.y*4+w)*4 .. +3 for 64 px. x read global-coalesced (L1 serves
// the 4 waves' repeats); w1T slice is one contiguous s_load_dwordx4/iter.
__global__ __launch_bounds__(256) void conv1_bn_relu(
    const float* __restrict__ x, const float* __restrict__ w1T,
    const float* __restrict__ gamma, const float* __restrict__ beta,
    const float* __restrict__ mean, const float* __restrict__ var,
    unsigned short* __restrict__ ybf)
{
    const int t    = threadIdx.x;
    const int lane = t & 63;
    const int og   = __builtin_amdgcn_readfirstlane(blockIdx.y * 4 + (t >> 6)); // 0..15
    const int tile = blockIdx.x;          // 0..195
    const int b    = tile / 49;
    const int hw   = (tile - b * 49) * 64 + lane;

    const float* __restrict__ xb = x + (size_t)b * C_IN * HW + hw;

    float acc[4] = {0.f, 0.f, 0.f, 0.f};
#pragma unroll 8
    for (int c = 0; c < C_IN; ++c) {
        const float xv = xb[(size_t)c * HW];
        const f32x4 wv = *(const f32x4*)(w1T + c * 64 + og * 4);   // uniform -> s_load_dwordx4
#pragma unroll
        for (int u = 0; u < 4; ++u) acc[u] += wv[u] * xv;
    }

    unsigned short o4[4];
#pragma unroll
    for (int u = 0; u < 4; ++u) {
        const int o = og * 4 + u;
        const float s  = gamma[o] * rsqrtf(var[o] + BN_EPS);
        const float sh = beta[o] - mean[o] * s;
        o4[u] = f2bf(fmaxf(acc[u] * s + sh, 0.f));
    }
    u32x2 pack;
    pack.x = (unsigned)o4[0] | ((unsigned)o4[1] << 16);
    pack.y = (unsigned)o4[2] | ((unsigned)o4[3] << 16);
    *(u32x2*)(ybf + ((size_t)(b * HW + hw)) * 64 + og * 4) = pack;
}

// ---- Kernel 2: MFMA conv2 + vectorized involution. 1 wave per block. ----
// Block = (b, g, 64-px tile), 64 threads.
// Phase 1: 32x mfma_f32_16x16x32_bf16 -> kw[64 taps][64 px] in LDS
//          (bias added, OOB taps zeroed).
// Phase 2: thread = (pg = tid&15 -> 4 px, cq = tid>>4 -> 4 ch).
//          Per (row i): 3 aligned float4 x-loads per ch cover the 12-float
//          window; per tap j: 1 ds_read_b128 gives kw for 4 px; extraction
//          is compile-time. Garbage edge elements hit kw==0 only.
__global__ __launch_bounds__(64) void conv2_involution(
    const float* __restrict__ x, const unsigned short* __restrict__ ybf,
    const unsigned short* __restrict__ wprep, const float* __restrict__ b2pad,
    float* __restrict__ out)
{
    __shared__ float kw_lds[64 * 64];   // [tap][px], 16 KB

    const int tid  = threadIdx.x;
    const int l15  = tid & 15;
    const int lg   = tid >> 4;
    const int tile = blockIdx.x;                 // 0..48
    const int g    = blockIdx.y & 15;
    const int b    = blockIdx.y >> 4;

    // ---- Phase 1: kw = W2g @ y  (per-pixel 64-tap kernels) ----
    {
        short8 Bf[4][2], Af[4][2];
#pragma unroll
        for (int ct = 0; ct < 4; ++ct) {
            const int hwp = tile * 64 + ct * 16 + l15;
            const unsigned short* yb = ybf + ((size_t)(b * HW + hwp)) * 64 + lg * 8;
            Bf[ct][0] = *(const short8*)(yb);
            Bf[ct][1] = *(const short8*)(yb + 32);
        }
#pragma unroll
        for (int rt = 0; rt < 4; ++rt) {
            const unsigned short* ar = wprep + g * 4096 + (rt * 16 + l15) * 64 + lg * 8;
            Af[rt][0] = *(const short8*)(ar);
            Af[rt][1] = *(const short8*)(ar + 32);
        }
        f32x4 acc[4][4];
#pragma unroll
        for (int ct = 0; ct < 4; ++ct)
#pragma unroll
            for (int rt = 0; rt < 4; ++rt) {
                acc[ct][rt] = (f32x4){0.f, 0.f, 0.f, 0.f};
                acc[ct][rt] = __builtin_amdgcn_mfma_f32_16x16x32_bf16(Af[rt][0], Bf[ct][0], acc[ct][rt], 0, 0, 0);
                acc[ct][rt] = __builtin_amdgcn_mfma_f32_16x16x32_bf16(Af[rt][1], Bf[ct][1], acc[ct][rt], 0, 0, 0);
            }

        // bias (vector loads, tiny + L1-hot)
        float bias[4][4];
#pragma unroll
        for (int rt = 0; rt < 4; ++rt)
#pragma unroll
            for (int r = 0; r < 4; ++r)
                bias[rt][r] = b2pad[g * 64 + rt * 16 + lg * 4 + r];

#pragma unroll
        for (int ct = 0; ct < 4; ++ct) {
            const int pxc = ct * 16 + l15;
            const int hwp = tile * 64 + pxc;
            const int hp  = hwp / WIDE;
            const int wp  = hwp - hp * WIDE;
#pragma unroll
            for (int rt = 0; rt < 4; ++rt)
#pragma unroll
                for (int r = 0; r < 4; ++r) {
                    const int k  = rt * 16 + lg * 4 + r;
                    const int i7 = k / 7, j7 = k - i7 * 7;
                    const int rr = hp + i7 - 3, cc = wp + j7 - 3;
                    const bool valid = (k < KK) & (rr >= 0) & (rr < WIDE) &
                                       (cc >= 0) & (cc < WIDE);
                    kw_lds[k * 64 + pxc] = valid ? (acc[ct][rt][r] + bias[rt][r]) : 0.f;
                }
        }
    }
    __syncthreads();

    // ---- Phase 2: involution, 4 px x 4 ch per thread ----
    const int pg  = tid & 15;
    const int cq  = tid >> 4;
    const int hw4 = tile * 64 + pg * 4;          // 4-aligned flat pixel base
    const int hrow = hw4 / WIDE;
    const int hcol = hw4 - hrow * WIDE;          // 4-aligned

    const float* bp[4];
#pragma unroll
    for (int c = 0; c < 4; ++c)
        bp[c] = x + ((size_t)b * C_IN + g * GC + cq * 4 + c) * HW;

    float acc[4][4];   // [ch][px]
#pragma unroll
    for (int c = 0; c < 4; ++c)
#pragma unroll
        for (int p = 0; p < 4; ++p) acc[c][p] = 0.f;

#pragma unroll
    for (int i = 0; i < 7; ++i) {
        const int rc    = min(max(hrow + i - 3, 0), WIDE - 1);  // v_med3
        const int basef = rc * WIDE + hcol;
        const int i0 = max(basef - 4, 0);
        const int i2 = min(basef + 4, HW - 4);

        float win[4][12];
#pragma unroll
        for (int c = 0; c < 4; ++c) {
            const f32x4 A0 = *(const f32x4*)(bp[c] + i0);
            const f32x4 A1 = *(const f32x4*)(bp[c] + basef);
            const f32x4 A2 = *(const f32x4*)(bp[c] + i2);
#pragma unroll
            for (int e = 0; e < 4; ++e) {
                win[c][e]     = A0[e];
                win[c][e + 4] = A1[e];
                win[c][e + 8] = A2[e];
            }
        }
#pragma unroll
        for (int j = 0; j < 7; ++j) {
            const f32x4 kw4 = *(const f32x4*)&kw_lds[(i * 7 + j) * 64 + pg * 4];
#pragma unroll
            for (int c = 0; c < 4; ++c)
#pragma unroll
                for (int p = 0; p < 4; ++p)
                    acc[c][p] += kw4[p] * win[c][p + j + 1];   // e = 4+(p+j-3)
        }
    }

#pragma unroll
    for (int c = 0; c < 4; ++c) {
        f32x4 st;
#pragma unroll
        for (int p = 0; p < 4; ++p) st[p] = acc[c][p];
        *(f32x4*)(out + ((size_t)b * C_IN + g * GC + cq * 4 + c) * HW + hw4) = st;
    }
}

extern "C" void kernel_launch(void* const* d_in, const int* in_sizes, int n_in,
                              void* d_out, int out_size, void* d_ws, size_t ws_size,
                              hipStream_t stream) {
    const float* x     = (const float*)d_in[0];
    const float* w1    = (const float*)d_in[1];
    const float* gamma = (const float*)d_in[2];
    const float* beta  = (const float*)d_in[3];
    const float* mean  = (const float*)d_in[4];
    const float* var   = (const float*)d_in[5];
    const float* w2    = (const float*)d_in[6];
    const float* b2    = (const float*)d_in[7];
    float* out = (float*)d_out;

    char* ws = (char*)d_ws;
    unsigned short* ybf   = (unsigned short*)(ws);             // 1,605,632 B
    unsigned short* wprep = (unsigned short*)(ws + 1605632);   //   131,072 B
    float*          b2pad = (float*)(ws + 1736704);            //     4,096 B
    float*          w1T   = (float*)(ws + 1740800);            //    65,536 B

    prep_kernel<<<dim3(256), dim3(256), 0, stream>>>(w1, w2, b2, w1T, wprep, b2pad);
    conv1_bn_relu<<<dim3(196, 4), dim3(256), 0, stream>>>(x, w1T, gamma, beta, mean, var, ybf);
    conv2_involution<<<dim3(49, 64), dim3(64), 0, stream>>>(x, ybf, wprep, b2pad, out);
}